// Round 9
// baseline (140.702 us; speedup 1.0000x reference)
//
#include <hip/hip_runtime.h>
#include <hip/hip_bf16.h>

typedef __bf16 bf16_t;
typedef bf16_t bf16x4 __attribute__((ext_vector_type(4)));
typedef bf16_t bf16x8 __attribute__((ext_vector_type(8)));
typedef float  f32x4  __attribute__((ext_vector_type(4)));

#define IN_F   1024
#define OUT_F  1024
#define RANK   8
#define NE     8
#define BATCH  32
#define SEQ    1024
#define M_TOT  (BATCH * SEQ)
#define SCALE  0.125f
#define NT     16   // K / 64

#define GLOAD_LDS16(g, l)                                                     \
  __builtin_amdgcn_global_load_lds(                                           \
      (const __attribute__((address_space(1))) void*)(g),                     \
      (__attribute__((address_space(3))) void*)(l), 16, 0, 0)

#define CFENCE asm volatile("" ::: "memory")
#define BAR()                                                                 \
  do { CFENCE; __builtin_amdgcn_s_barrier(); CFENCE; } while (0)
#define VMCNT(n) asm volatile("s_waitcnt vmcnt(" #n ")" ::: "memory")

// ---------------------------------------------------------------------------
// Kernel 1: build weff in FRAGMENT ORDER.
// Line L (14 bits: e[3] nb[2] kt[4] kh[1] wn[2] ni[2]); one wave per line.
// Lane l computes the 8 bf16 elems of fragment position (l&15 = row-in-16,
// l>>4 = k-octet): o = nb*256+wn*64+ni*16+(l&15), k = kt*64+kh*32+(l>>4)*8+j.
// Store: wfrag[L*512 + l*8 .. +8)  (1 KB contiguous per wave).
// ---------------------------------------------------------------------------
__global__ __launch_bounds__(256) void build_frag(
    const float* __restrict__ W, const float* __restrict__ A,
    const float* __restrict__ Bw, bf16_t* __restrict__ wfrag) {
  const int wid = threadIdx.x >> 6, lane = threadIdx.x & 63;
  const int L = (blockIdx.x << 2) + wid;
  const int e  = L >> 11;
  const int nb = (L >> 9) & 3;
  const int kt = (L >> 5) & 15;
  const int kh = (L >> 4) & 1;
  const int wn = (L >> 2) & 3;
  const int ni = L & 3;
  const int o  = (nb << 8) + (wn << 6) + (ni << 4) + (lane & 15);
  const int kb = (kt << 6) + (kh << 5) + ((lane >> 4) << 3);

  const float* wrow = W + ((size_t)o << 10) + kb;
  f32x4 s0 = *(const f32x4*)(wrow);
  f32x4 s1 = *(const f32x4*)(wrow + 4);
  const float* bwr = Bw + ((((size_t)e << 10) + o) << 3);
  const float* ab  = A + (((size_t)e << 3) << 10) + kb;
#pragma unroll
  for (int r = 0; r < RANK; ++r) {
    const float c = SCALE * bwr[r];
    s0 += c * *(const f32x4*)(ab + ((size_t)r << 10));
    s1 += c * *(const f32x4*)(ab + ((size_t)r << 10) + 4);
  }
  bf16x8 v;
#pragma unroll
  for (int j = 0; j < 4; ++j) { v[j] = (bf16_t)s0[j]; v[4 + j] = (bf16_t)s1[j]; }
  *(bf16x8*)(wfrag + ((size_t)L << 9) + (lane << 3)) = v;
}

// ---------------------------------------------------------------------------
// Kernel 2: x fp32 -> bf16
// ---------------------------------------------------------------------------
__global__ __launch_bounds__(256) void cvt_x(const float* __restrict__ x,
                                             bf16_t* __restrict__ xb, int n4) {
  int i = blockIdx.x * 256 + threadIdx.x;
  const int stride = gridDim.x * 256;
  for (; i < n4; i += stride) {
    const f32x4 v = *(const f32x4*)(x + ((size_t)i << 2));
    bf16x4 o;
#pragma unroll
    for (int j = 0; j < 4; ++j) o[j] = (bf16_t)v[j];
    *(bf16x4*)(xb + ((size_t)i << 2)) = o;
  }
}

// ---------------------------------------------------------------------------
// Kernel 3: 256x256, BK=64, 8 waves. A: gload_lds + swizzle (R2-proven).
// B: NO LDS — fragment-ordered weff loaded straight to regs from L2
// (1 coalesced dwordx4 per frag per wave). One barrier per K-tile:
//   tile j: RD af(kh0); issue B(j+1)->other set (8 ld) + A(j+1)->other buf
//   (4 gload_lds); MFMA kh0; RD af(kh1); MFMA kh1; VMCNT(0); BAR.
// Cover for the drain = full tile (~2500 cy) >> HBM 900 / L2 200.
// LDS traffic halved vs R2-R7 (A only): reads 1536cy + writes 256cy < MFMA.
// ---------------------------------------------------------------------------
__global__ __launch_bounds__(512, 2) void gemm256(
    const bf16_t* __restrict__ xb, const bf16_t* __restrict__ wfrag,
    const float* __restrict__ bias, const int* __restrict__ sid,
    float* __restrict__ out) {
  __shared__ bf16_t lds_a[2][2][8192];  // [buf][kh][256r x 32k] = 64 KiB

  const int bid0 = blockIdx.x;
  const int wgid = ((bid0 & 7) << 6) + (bid0 >> 3);  // XCD chunked (512 wgs)
  const int mb = wgid >> 2, nb = wgid & 3;
  const int m0 = mb << 8;
  const int e = sid[mb >> 2];

  const int tid = threadIdx.x;
  const int lane = tid & 63, wid = tid >> 6;
  const int wm = wid >> 2, wn = wid & 3;

  const bf16_t* agbase = xb + ((size_t)m0 << 10);
  // B frag base for this wave: [e][nb] panel + wn + lane
  const bf16_t* bgf = wfrag + ((((size_t)e << 2) + nb) << 18) + (wn << 11) +
                      (lane << 3);

  // A staging offsets (R2-proven): instr i covers LDS row r=wid*32+i*16+
  // (lane>>2), granule lane&3 linear; source granule pre-swizzled.
  int soff[2];
#pragma unroll
  for (int i = 0; i < 2; ++i) {
    const int r = (wid << 5) + (i << 4) + (lane >> 2);
    const int sg = (lane & 3) ^ ((r >> 1) & 3);
    soff[i] = (r << 10) + (sg << 3);
  }
  // A fragment read offsets (R2-proven swizzle) within one [256][32] region
  int aoff[8];
#pragma unroll
  for (int mi = 0; mi < 8; ++mi) {
    const int r = (wm << 7) + (mi << 4) + (lane & 15);
    const int g = (lane >> 4) ^ ((r >> 1) & 3);
    aoff[mi] = (r << 5) + (g << 3);
  }

  f32x4 acc[8][4] = {};
  bf16x8 af[8], bfr[2][2][4];  // [set][kh][ni]

#define ASTG(kt, c)                                                           \
  do {                                                                        \
    const int _k0 = (kt) << 6;                                                \
    bf16_t* _d0 = &lds_a[c][0][wid << 10];                                    \
    bf16_t* _d1 = &lds_a[c][1][wid << 10];                                    \
    GLOAD_LDS16(agbase + _k0 + soff[0], _d0);                                 \
    GLOAD_LDS16(agbase + _k0 + soff[1], _d0 + 512);                           \
    GLOAD_LDS16(agbase + _k0 + 32 + soff[0], _d1);                            \
    GLOAD_LDS16(agbase + _k0 + 32 + soff[1], _d1 + 512);                      \
  } while (0)

#define BLOAD(kt, S)                                                          \
  do {                                                                        \
    const bf16_t* _p = bgf + ((size_t)(kt) << 14);                            \
    _Pragma("unroll") for (int _n = 0; _n < 4; ++_n)                          \
        bfr[S][0][_n] = *(const bf16x8*)(_p + (_n << 9));                     \
    _Pragma("unroll") for (int _n = 0; _n < 4; ++_n)                          \
        bfr[S][1][_n] = *(const bf16x8*)(_p + 8192 + (_n << 9));              \
  } while (0)

#define RD(c, kh)                                                             \
  do {                                                                        \
    const bf16_t* _ab = &lds_a[c][kh][0];                                     \
    _Pragma("unroll") for (int mi = 0; mi < 8; ++mi)                          \
        af[mi] = *(const bf16x8*)(_ab + aoff[mi]);                            \
  } while (0)

#define MM(S, kh)                                                             \
  do {                                                                        \
    __builtin_amdgcn_s_setprio(1);                                            \
    _Pragma("unroll") for (int mi = 0; mi < 8; ++mi)                          \
        _Pragma("unroll") for (int ni = 0; ni < 4; ++ni)                      \
            acc[mi][ni] = __builtin_amdgcn_mfma_f32_16x16x32_bf16(            \
                af[mi], bfr[S][kh][ni], acc[mi][ni], 0, 0, 0);                \
    __builtin_amdgcn_s_setprio(0);                                            \
  } while (0)

#define TILE(J, C, S, NXT, DO_ISSUE)                                          \
  do {                                                                        \
    RD(C, 0);                                                                 \
    if (DO_ISSUE) { BLOAD((J) + 1, NXT); ASTG((J) + 1, 1 - (C)); }            \
    MM(S, 0);                                                                 \
    RD(C, 1);                                                                 \
    MM(S, 1);                                                                 \
    if (DO_ISSUE) { VMCNT(0); BAR(); }                                        \
  } while (0)

  // prologue: B(0)->set0, A(0)->buf0
  BLOAD(0, 0);
  ASTG(0, 0);
  VMCNT(0);
  BAR();

  for (int jj = 0; jj < 7; ++jj) {
    const int j0 = jj << 1;
    TILE(j0, 0, 0, 1, 1);
    TILE(j0 + 1, 1, 1, 0, 1);
  }
  TILE(14, 0, 0, 1, 1);
  TILE(15, 1, 1, 0, 0);  // no issue, no trailing wait

  // epilogue: C/D layout col=lane&15, row=(lane>>4)*4+j
  const int R0 = m0 + (wm << 7);
  const int C0 = (nb << 8) + (wn << 6);
  const int crow = (lane >> 4) << 2;
  const int ccol = lane & 15;
#pragma unroll
  for (int ni = 0; ni < 4; ++ni) {
    const int col = C0 + (ni << 4) + ccol;
    const float bv = bias[col];
#pragma unroll
    for (int mi = 0; mi < 8; ++mi) {
      const int row = R0 + (mi << 4) + crow;
#pragma unroll
      for (int j2 = 0; j2 < 4; ++j2)
        out[((size_t)(row + j2) << 10) + col] = acc[mi][ni][j2] + bv;
    }
  }
#undef ASTG
#undef BLOAD
#undef RD
#undef MM
#undef TILE
}

// ---------------------------------------------------------------------------
// Fallback (ws too small): naive fp32.
// ---------------------------------------------------------------------------
__global__ __launch_bounds__(256) void lora_naive(
    const float* __restrict__ x, const float* __restrict__ W,
    const float* __restrict__ bias, const float* __restrict__ A,
    const float* __restrict__ Bw, const int* __restrict__ sid,
    float* __restrict__ out) {
  const int m = blockIdx.x;
  const int e = sid[m >> 10];
  __shared__ float xs[IN_F];
  __shared__ float h[RANK];
  const int tid = threadIdx.x;
  for (int i = tid; i < IN_F; i += 256) xs[i] = x[((size_t)m << 10) + i];
  __syncthreads();
  if (tid < RANK) {
    float s = 0.f;
    const float* ar = A + (((size_t)e * RANK + tid) << 10);
    for (int d = 0; d < IN_F; ++d) s += xs[d] * ar[d];
    h[tid] = s * SCALE;
  }
  __syncthreads();
  for (int o = tid; o < OUT_F; o += 256) {
    const float* wr = W + ((size_t)o << 10);
    float s = 0.f;
    for (int d = 0; d < IN_F; ++d) s += xs[d] * wr[d];
    const float* bwr = Bw + (((size_t)e << 10) + o) * RANK;
    float l = 0.f;
#pragma unroll
    for (int r = 0; r < RANK; ++r) l += h[r] * bwr[r];
    out[((size_t)m << 10) + o] = s + bias[o] + l;
  }
}

extern "C" void kernel_launch(void* const* d_in, const int* in_sizes, int n_in,
                              void* d_out, int out_size, void* d_ws,
                              size_t ws_size, hipStream_t stream) {
  const float* x   = (const float*)d_in[0];
  const float* W   = (const float*)d_in[1];
  const float* b   = (const float*)d_in[2];
  const float* A   = (const float*)d_in[3];
  const float* Bw  = (const float*)d_in[4];
  const int*   sid = (const int*)d_in[5];
  float* out = (float*)d_out;

  const size_t wfrag_bytes = (size_t)NE * OUT_F * IN_F * 2;  // 16 MiB
  const size_t xb_bytes    = (size_t)M_TOT * IN_F * 2;       // 64 MiB

  if (ws_size >= wfrag_bytes + xb_bytes) {
    bf16_t* wfrag = (bf16_t*)d_ws;
    bf16_t* xb    = (bf16_t*)((char*)d_ws + wfrag_bytes);
    hipLaunchKernelGGL(build_frag, dim3(4096), dim3(256), 0, stream,
                       W, A, Bw, wfrag);
    hipLaunchKernelGGL(cvt_x, dim3(4096), dim3(256), 0, stream,
                       x, xb, M_TOT * IN_F / 4);
    hipLaunchKernelGGL(gemm256, dim3((M_TOT / 256) * (OUT_F / 256)),
                       dim3(512), 0, stream, xb, wfrag, b, sid, out);
  } else {
    hipLaunchKernelGGL(lora_naive, dim3(M_TOT), dim3(256), 0, stream,
                       x, W, b, A, Bw, sid, out);
  }
}

// Round 10
// 134.787 us; speedup vs baseline: 1.0439x; 1.0439x over previous
//
#include <hip/hip_runtime.h>
#include <hip/hip_bf16.h>

typedef __bf16 bf16_t;
typedef bf16_t bf16x4 __attribute__((ext_vector_type(4)));
typedef bf16_t bf16x8 __attribute__((ext_vector_type(8)));
typedef float  f32x4  __attribute__((ext_vector_type(4)));

#define IN_F   1024
#define OUT_F  1024
#define RANK   8
#define NE     8
#define BATCH  32
#define SEQ    1024
#define M_TOT  (BATCH * SEQ)
#define SCALE  0.125f
#define NT     16   // K / 64

#define GLOAD_LDS16(g, l)                                                     \
  __builtin_amdgcn_global_load_lds(                                           \
      (const __attribute__((address_space(1))) void*)(g),                     \
      (__attribute__((address_space(3))) void*)(l), 16, 0, 0)

#define CFENCE asm volatile("" ::: "memory")
#define BAR()                                                                 \
  do { CFENCE; __builtin_amdgcn_s_barrier(); CFENCE; } while (0)
#define VMCNT(n) asm volatile("s_waitcnt vmcnt(" #n ")" ::: "memory")

// ---------------------------------------------------------------------------
// Kernel 1: build weff in FRAGMENT ORDER (R9-proven).
// Line L: e[3] nb[2] kt[4] kh[1] wn[2] ni[2]; lane l -> o=nb*256+wn*64+ni*16+
// (l&15), k=kt*64+kh*32+(l>>4)*8+j. Store wfrag[L*512 + l*8 ..].
// ---------------------------------------------------------------------------
__global__ __launch_bounds__(256) void build_frag(
    const float* __restrict__ W, const float* __restrict__ A,
    const float* __restrict__ Bw, bf16_t* __restrict__ wfrag) {
  const int wid = threadIdx.x >> 6, lane = threadIdx.x & 63;
  const int L = (blockIdx.x << 2) + wid;
  const int e  = L >> 11;
  const int nb = (L >> 9) & 3;
  const int kt = (L >> 5) & 15;
  const int kh = (L >> 4) & 1;
  const int wn = (L >> 2) & 3;
  const int ni = L & 3;
  const int o  = (nb << 8) + (wn << 6) + (ni << 4) + (lane & 15);
  const int kb = (kt << 6) + (kh << 5) + ((lane >> 4) << 3);

  const float* wrow = W + ((size_t)o << 10) + kb;
  f32x4 s0 = *(const f32x4*)(wrow);
  f32x4 s1 = *(const f32x4*)(wrow + 4);
  const float* bwr = Bw + ((((size_t)e << 10) + o) << 3);
  const float* ab  = A + (((size_t)e << 3) << 10) + kb;
#pragma unroll
  for (int r = 0; r < RANK; ++r) {
    const float c = SCALE * bwr[r];
    s0 += c * *(const f32x4*)(ab + ((size_t)r << 10));
    s1 += c * *(const f32x4*)(ab + ((size_t)r << 10) + 4);
  }
  bf16x8 v;
#pragma unroll
  for (int j = 0; j < 4; ++j) { v[j] = (bf16_t)s0[j]; v[4 + j] = (bf16_t)s1[j]; }
  *(bf16x8*)(wfrag + ((size_t)L << 9) + (lane << 3)) = v;
}

// ---------------------------------------------------------------------------
// Kernel 2: 256x256, BK=64, 8 waves. NO x pre-conversion: A staged as FP32
// via global_load_lds (dbuf [2][256r x 64k f32] = 128 KiB), fragments
// ds_read as f32x4 pairs and cast to bf16 at use (same RNE as cvt_x).
// B: fragment-ordered weff straight to regs from L2 (R9-proven).
// One barrier per K-tile; VMCNT(0) drain covered by a full tile (T4-safe).
// A-swizzle (fp32): granule = 8 f32 (32 B), stored pos p holds src granule
// p^(r&7); write linear dest + pre-swizzled source; read pos (kh*4+o)^(r&7).
// ---------------------------------------------------------------------------
__global__ __launch_bounds__(512, 2) void gemm256(
    const float* __restrict__ xf, const bf16_t* __restrict__ wfrag,
    const float* __restrict__ bias, const int* __restrict__ sid,
    float* __restrict__ out) {
  __shared__ float lds_af[2][16384];  // [buf][256][64] f32, 128 KiB

  const int bid0 = blockIdx.x;
  const int wgid = ((bid0 & 7) << 6) + (bid0 >> 3);  // XCD chunked (512 wgs)
  const int mb = wgid >> 2, nb = wgid & 3;
  const int m0 = mb << 8;
  const int e = sid[mb >> 2];

  const int tid = threadIdx.x;
  const int lane = tid & 63, wid = tid >> 6;
  const int wm = wid >> 2, wn = wid & 3;

  const float* agf = xf + ((size_t)m0 << 10);
  const bf16_t* bgf = wfrag + ((((size_t)e << 2) + nb) << 18) + (wn << 11) +
                      (lane << 3);

  // A staging: instr i covers rows w*32+i*4 .. +4 (1 KiB linear dest).
  // lane -> row r = w*32+i*4+(lane>>4), granule g=(lane&15)>>1, half h=lane&1.
  // source elem = r*1024 + (g^(r&7))*8 + h*4  (+ kt*64).
  // i and i+2 differ by +8 rows: +8192 elems, same r&7 -> 2 stored offsets.
  int soff[2];
#pragma unroll
  for (int i = 0; i < 2; ++i) {
    const int r = (wid << 5) + (i << 2) + (lane >> 4);
    const int g = ((lane & 15) >> 1) ^ (r & 7);
    soff[i] = (r << 10) + (g << 3) + ((lane & 1) << 2);
  }
  // A fragment read: row r, content granule s = kh*4+(lane>>4) at stored pos
  // s^(r&7); elem off = r*64 + pos*8; kh toggles via XOR 32 (bit 5 of pos<<3).
  int aoff[8];
#pragma unroll
  for (int mi = 0; mi < 8; ++mi) {
    const int r = (wm << 7) + (mi << 4) + (lane & 15);
    const int p = (lane >> 4) ^ (r & 7);
    aoff[mi] = (r << 6) + (p << 3);
  }

  f32x4 acc[8][4] = {};
  bf16x8 bfr[2][2][4];  // [set][kh][ni]

#define ASTG(kt, c)                                                           \
  do {                                                                        \
    float* _d = &lds_af[c][wid << 11];                                        \
    const int _k = (kt) << 6;                                                 \
    _Pragma("unroll") for (int i = 0; i < 8; ++i)                             \
        GLOAD_LDS16(agf + _k + soff[i & 1] + ((i >> 1) << 13),                \
                    _d + (i << 8));                                           \
  } while (0)

#define BLOAD(kt, S)                                                          \
  do {                                                                        \
    const bf16_t* _p = bgf + ((size_t)(kt) << 14);                            \
    _Pragma("unroll") for (int _n = 0; _n < 4; ++_n)                          \
        bfr[S][0][_n] = *(const bf16x8*)(_p + (_n << 9));                     \
    _Pragma("unroll") for (int _n = 0; _n < 4; ++_n)                          \
        bfr[S][1][_n] = *(const bf16x8*)(_p + 8192 + (_n << 9));              \
  } while (0)

// per-fragment: 2 ds_read(f32x4) -> cvt bf16x8 -> 4 MFMA (temps recycle)
#define KSTEP(c, kh, S)                                                       \
  do {                                                                        \
    const float* _ab = &lds_af[c][0];                                         \
    _Pragma("unroll") for (int mi = 0; mi < 8; ++mi) {                        \
      const int _o = aoff[mi] ^ ((kh) << 5);                                  \
      const f32x4 _lo = *(const f32x4*)(_ab + _o);                            \
      const f32x4 _hi = *(const f32x4*)(_ab + _o + 4);                        \
      bf16x8 _a8;                                                             \
      _Pragma("unroll") for (int _j = 0; _j < 4; ++_j) {                      \
        _a8[_j] = (bf16_t)_lo[_j]; _a8[4 + _j] = (bf16_t)_hi[_j];             \
      }                                                                       \
      __builtin_amdgcn_s_setprio(1);                                          \
      _Pragma("unroll") for (int ni = 0; ni < 4; ++ni)                        \
          acc[mi][ni] = __builtin_amdgcn_mfma_f32_16x16x32_bf16(              \
              _a8, bfr[S][kh][ni], acc[mi][ni], 0, 0, 0);                     \
      __builtin_amdgcn_s_setprio(0);                                          \
    }                                                                         \
  } while (0)

#define TILE(J, C, S, NXT, DO_ISSUE)                                          \
  do {                                                                        \
    if (DO_ISSUE) { BLOAD((J) + 1, NXT); ASTG((J) + 1, 1 - (C)); }            \
    KSTEP(C, 0, S);                                                           \
    KSTEP(C, 1, S);                                                           \
    if (DO_ISSUE) { VMCNT(0); BAR(); }                                        \
  } while (0)

  // prologue
  BLOAD(0, 0);
  ASTG(0, 0);
  VMCNT(0);
  BAR();

  for (int jj = 0; jj < 7; ++jj) {
    const int j0 = jj << 1;
    TILE(j0, 0, 0, 1, 1);
    TILE(j0 + 1, 1, 1, 0, 1);
  }
  TILE(14, 0, 0, 1, 1);
  TILE(15, 1, 1, 0, 0);

  // epilogue: C/D layout col=lane&15, row=(lane>>4)*4+j
  const int R0 = m0 + (wm << 7);
  const int C0 = (nb << 8) + (wn << 6);
  const int crow = (lane >> 4) << 2;
  const int ccol = lane & 15;
#pragma unroll
  for (int ni = 0; ni < 4; ++ni) {
    const int col = C0 + (ni << 4) + ccol;
    const float bv = bias[col];
#pragma unroll
    for (int mi = 0; mi < 8; ++mi) {
      const int row = R0 + (mi << 4) + crow;
#pragma unroll
      for (int j2 = 0; j2 < 4; ++j2)
        out[((size_t)(row + j2) << 10) + col] = acc[mi][ni][j2] + bv;
    }
  }
#undef ASTG
#undef BLOAD
#undef KSTEP
#undef TILE
}

// ---------------------------------------------------------------------------
// Fallback (ws too small): naive fp32.
// ---------------------------------------------------------------------------
__global__ __launch_bounds__(256) void lora_naive(
    const float* __restrict__ x, const float* __restrict__ W,
    const float* __restrict__ bias, const float* __restrict__ A,
    const float* __restrict__ Bw, const int* __restrict__ sid,
    float* __restrict__ out) {
  const int m = blockIdx.x;
  const int e = sid[m >> 10];
  __shared__ float xs[IN_F];
  __shared__ float h[RANK];
  const int tid = threadIdx.x;
  for (int i = tid; i < IN_F; i += 256) xs[i] = x[((size_t)m << 10) + i];
  __syncthreads();
  if (tid < RANK) {
    float s = 0.f;
    const float* ar = A + (((size_t)e * RANK + tid) << 10);
    for (int d = 0; d < IN_F; ++d) s += xs[d] * ar[d];
    h[tid] = s * SCALE;
  }
  __syncthreads();
  for (int o = tid; o < OUT_F; o += 256) {
    const float* wr = W + ((size_t)o << 10);
    float s = 0.f;
    for (int d = 0; d < IN_F; ++d) s += xs[d] * wr[d];
    const float* bwr = Bw + (((size_t)e << 10) + o) * RANK;
    float l = 0.f;
#pragma unroll
    for (int r = 0; r < RANK; ++r) l += h[r] * bwr[r];
    out[((size_t)m << 10) + o] = s + bias[o] + l;
  }
}

extern "C" void kernel_launch(void* const* d_in, const int* in_sizes, int n_in,
                              void* d_out, int out_size, void* d_ws,
                              size_t ws_size, hipStream_t stream) {
  const float* x   = (const float*)d_in[0];
  const float* W   = (const float*)d_in[1];
  const float* b   = (const float*)d_in[2];
  const float* A   = (const float*)d_in[3];
  const float* Bw  = (const float*)d_in[4];
  const int*   sid = (const int*)d_in[5];
  float* out = (float*)d_out;

  const size_t wfrag_bytes = (size_t)NE * OUT_F * IN_F * 2;  // 16 MiB

  if (ws_size >= wfrag_bytes) {
    bf16_t* wfrag = (bf16_t*)d_ws;
    hipLaunchKernelGGL(build_frag, dim3(4096), dim3(256), 0, stream,
                       W, A, Bw, wfrag);
    hipLaunchKernelGGL(gemm256, dim3((M_TOT / 256) * (OUT_F / 256)),
                       dim3(512), 0, stream, x, wfrag, b, sid, out);
  } else {
    hipLaunchKernelGGL(lora_naive, dim3(M_TOT), dim3(256), 0, stream,
                       x, W, b, A, Bw, sid, out);
  }
}